// Round 17
// baseline (441.830 us; speedup 1.0000x reference)
//
#include <hip/hip_runtime.h>

constexpr int TIN = 50;
constexpr int BLK = 256;
constexpr float NEG_LOG2E = -1.44269504088896341f;

typedef float floatx4 __attribute__((ext_vector_type(4)));

// ws float layout (16B-aligned, gate-major, 10->12 pad so quads are single-gate).
// k = gate*12 + j, gate {0:i,1:f,2:g,3:o}; i/f/o cols pre-scaled by -log2(e)
// so sigmoid(z) = rcp(1 + exp2(z')).
//   0    R1p[10][48]
//   480  W1p[48]
//   528  b1p[48]
//   576  W2p[10][48]
//   1056 b2p[48]
//   1104 R2p[10][48]
//   1584 Wdp[12]
constexpr int WS_FLOATS = 1596;

__global__ void prep_weights(const float* __restrict__ W1, const float* __restrict__ R1,
                             const float* __restrict__ b1, const float* __restrict__ W2,
                             const float* __restrict__ R2, const float* __restrict__ b2,
                             const float* __restrict__ Wd, float* __restrict__ ws)
{
    const int tid = threadIdx.x;
    for (int i = tid; i < 480; i += BLK) {
        const int u = i / 48, k = i % 48, gate = k / 12, j = k % 12;
        const float sg = (gate == 2) ? 1.0f : NEG_LOG2E;
        ws[i]        = (j < 10) ? R1[u * 40 + gate * 10 + j] * sg : 0.0f;
        ws[576 + i]  = (j < 10) ? W2[u * 40 + gate * 10 + j] * sg : 0.0f;
        ws[1104 + i] = (j < 10) ? R2[u * 40 + gate * 10 + j] * sg : 0.0f;
    }
    for (int k = tid; k < 48; k += BLK) {
        const int gate = k / 12, j = k % 12;
        const float sg = (gate == 2) ? 1.0f : NEG_LOG2E;
        ws[480 + k]  = (j < 10) ? W1[gate * 10 + j] * sg : 0.0f;
        ws[528 + k]  = (j < 10) ? b1[gate * 10 + j] * sg : 0.0f;
        ws[1056 + k] = (j < 10) ? b2[gate * 10 + j] * sg : 0.0f;
    }
    if (tid < 12) ws[1584 + tid] = (tid < 10) ? Wd[tid] : 0.0f;
}

#define EFMA __builtin_elementwise_fma
#define EMAX __builtin_elementwise_max
#define SB   __builtin_amdgcn_sched_barrier(0);

#define SIGQ(dst, src)                                                        \
    dst[0] = __builtin_amdgcn_rcpf(1.0f + __builtin_amdgcn_exp2f((src)[0]));  \
    dst[1] = __builtin_amdgcn_rcpf(1.0f + __builtin_amdgcn_exp2f((src)[1]));  \
    dst[2] = __builtin_amdgcn_rcpf(1.0f + __builtin_amdgcn_exp2f((src)[2]));  \
    dst[3] = __builtin_amdgcn_rcpf(1.0f + __builtin_amdgcn_exp2f((src)[3]));

#define SIG3(d0, d1, d2, s0, s1, s2) SIGQ(d0, s0) SIGQ(d1, s1) SIGQ(d2, s2)

// ---------------- single-element building blocks (tail; = round 10/14) ------
#define RECQ(RB, g, u, HV, t0, t1, t2)                                        \
    {   const float h_ = (HV);                                                \
        const floatx4 hs_ = {h_, h_, h_, h_};                                 \
        t0 = EFMA(hs_, RB[(u) * 12 + (g) * 3 + 0], t0);                       \
        t1 = EFMA(hs_, RB[(u) * 12 + (g) * 3 + 1], t1);                       \
        t2 = EFMA(hs_, RB[(u) * 12 + (g) * 3 + 2], t2); }

#define REC10(RB, g, H0, H1, H2, t0, t1, t2)                                  \
    RECQ(RB, g, 0, (H0)[0], t0, t1, t2) RECQ(RB, g, 1, (H0)[1], t0, t1, t2) SB\
    RECQ(RB, g, 2, (H0)[2], t0, t1, t2) RECQ(RB, g, 3, (H0)[3], t0, t1, t2) SB\
    RECQ(RB, g, 4, (H1)[0], t0, t1, t2) RECQ(RB, g, 5, (H1)[1], t0, t1, t2) SB\
    RECQ(RB, g, 6, (H1)[2], t0, t1, t2) RECQ(RB, g, 7, (H1)[3], t0, t1, t2) SB\
    RECQ(RB, g, 8, (H2)[0], t0, t1, t2) RECQ(RB, g, 9, (H2)[1], t0, t1, t2) SB

#define XZG(g, x0, x1, x2)                                                    \
    x0 = B2q_[(g) * 3 + 0]; x1 = B2q_[(g) * 3 + 1]; x2 = B2q_[(g) * 3 + 2];   \
    REC10(W2q_, g, hq0, hq1, hq2, x0, x1, x2)

#define GATE2(g, i0, i1, i2, t0, t1, t2)                                      \
    t0 = i0; t1 = i1; t2 = i2;                                                \
    REC10(R2q_, g, ho0, ho1, ho2, t0, t1, t2)

#define STEP2T                                                                \
    {   const floatx4 ho0 = h2q0, ho1 = h2q1, ho2 = h2q2;                     \
        floatx4 tt0, tt1, tt2, pp0, pp1, pp2, qq0, qq1, qq2;                  \
        GATE2(2, xqg0, xqg1, xqg2, tt0, tt1, tt2)                             \
        pp0 = EMAX(tt0, zero4); pp1 = EMAX(tt1, zero4);                       \
        pp2 = EMAX(tt2, zero4); SB                                            \
        GATE2(0, xqi0, xqi1, xqi2, tt0, tt1, tt2)                             \
        SIG3(qq0, qq1, qq2, tt0, tt1, tt2)                                    \
        pp0 *= qq0; pp1 *= qq1; pp2 *= qq2; SB                                \
        GATE2(1, xqf0, xqf1, xqf2, tt0, tt1, tt2)                             \
        SIG3(qq0, qq1, qq2, tt0, tt1, tt2)                                    \
        c2q0 = EFMA(qq0, c2q0, pp0); c2q1 = EFMA(qq1, c2q1, pp1);             \
        c2q2 = EFMA(qq2, c2q2, pp2); SB                                       \
        GATE2(3, xqo0, xqo1, xqo2, tt0, tt1, tt2)                             \
        SIG3(qq0, qq1, qq2, tt0, tt1, tt2)                                    \
        h2q0 = qq0 * EMAX(c2q0, zero4); h2q1 = qq1 * EMAX(c2q1, zero4);       \
        h2q2 = qq2 * EMAX(c2q2, zero4); SB                                    \
    }

#define DOUT(dst)                                                             \
    {   floatx4 dv_ = h2q0 * Wdq_[0];                                         \
        dv_ = EFMA(h2q1, Wdq_[1], dv_);                                       \
        dv_ = EFMA(h2q2, Wdq_[2], dv_);                                       \
        dst = dv_[0] + dv_[1] + dv_[2] + dv_[3] + bd0; }

// RepeatVector(3) + LSTM2 + Dense for ONE element (all names compile-time)
__device__ __forceinline__ void tail_one(const float* __restrict__ smem,
                                         floatx4 hq0, floatx4 hq1, floatx4 hq2,
                                         float bd0, float* __restrict__ o3)
{
    const floatx4 zero4 = {0.0f, 0.0f, 0.0f, 0.0f};
    const floatx4* W2q_ = (const floatx4*)(smem + 576);
    const floatx4* B2q_ = (const floatx4*)(smem + 1056);
    const floatx4* R2q_ = (const floatx4*)(smem + 1104);
    const floatx4* Wdq_ = (const floatx4*)(smem + 1584);

    floatx4 xqi0, xqi1, xqi2, xqf0, xqf1, xqf2;
    floatx4 xqg0, xqg1, xqg2, xqo0, xqo1, xqo2;
    XZG(0, xqi0, xqi1, xqi2) SB
    XZG(1, xqf0, xqf1, xqf2) SB
    XZG(2, xqg0, xqg1, xqg2) SB
    XZG(3, xqo0, xqo1, xqo2) SB

    floatx4 c2q0, c2q1, c2q2, h2q0, h2q1, h2q2, q0, q1, q2, s0, s1, s2;
    SIG3(q0, q1, q2, xqi0, xqi1, xqi2)
    c2q0 = q0 * EMAX(xqg0, zero4);
    c2q1 = q1 * EMAX(xqg1, zero4);
    c2q2 = q2 * EMAX(xqg2, zero4);
    SIG3(s0, s1, s2, xqo0, xqo1, xqo2)
    h2q0 = s0 * EMAX(c2q0, zero4);
    h2q1 = s1 * EMAX(c2q1, zero4);
    h2q2 = s2 * EMAX(c2q2, zero4);
    float o0; DOUT(o0)
    float o1; STEP2T DOUT(o1)
    float o2; STEP2T DOUT(o2)
    o3[0] = o0; o3[1] = o1; o3[2] = o2;
}

// ---------------- M=2 main-loop blocks with 2-unit lookahead ----------------
// LDU: issue 3 shared quad loads for unit u into a named 3-quad set.
#define LDU(RB, g, u, d0, d1, d2)                                             \
    d0 = RB[(u) * 12 + (g) * 3 + 0];                                          \
    d1 = RB[(u) * 12 + (g) * 3 + 1];                                          \
    d2 = RB[(u) * 12 + (g) * 3 + 2];

// FMAU: consume one 3-quad set for both elements (12 scalar FMAs).
#define FMAU(HA, HB, r0, r1, r2)                                              \
    {   const float ha_ = (HA), hb_ = (HB);                                   \
        const floatx4 hav_ = {ha_, ha_, ha_, ha_};                            \
        const floatx4 hbv_ = {hb_, hb_, hb_, hb_};                            \
        tA0 = EFMA(hav_, r0, tA0); tB0 = EFMA(hbv_, r0, tB0);                 \
        tA1 = EFMA(hav_, r1, tA1); tB1 = EFMA(hbv_, r1, tB1);                 \
        tA2 = EFMA(hav_, r2, tA2); tB2 = EFMA(hbv_, r2, tB2); }

// Windows: {load u+2 ; FMA u ; SB} — 3-set (ra/rb/rc) rotation gives a
// load-to-use distance of TWO full windows (~60 cy), covering the LDS
// latency. Only two prefetched sets (24 regs) live across each SB.
#define REC10_2T(RB, g)                                                       \
    LDU(RB, g, 2, rc0, rc1, rc2) FMAU(hA0[0], hB0[0], ra0, ra1, ra2) SB       \
    LDU(RB, g, 3, ra0, ra1, ra2) FMAU(hA0[1], hB0[1], rb0, rb1, rb2) SB       \
    LDU(RB, g, 4, rb0, rb1, rb2) FMAU(hA0[2], hB0[2], rc0, rc1, rc2) SB       \
    LDU(RB, g, 5, rc0, rc1, rc2) FMAU(hA0[3], hB0[3], ra0, ra1, ra2) SB       \
    LDU(RB, g, 6, ra0, ra1, ra2) FMAU(hA1[0], hB1[0], rb0, rb1, rb2) SB       \
    LDU(RB, g, 7, rb0, rb1, rb2) FMAU(hA1[1], hB1[1], rc0, rc1, rc2) SB       \
    LDU(RB, g, 8, rc0, rc1, rc2) FMAU(hA1[2], hB1[2], ra0, ra1, ra2) SB       \
    LDU(RB, g, 9, ra0, ra1, ra2) FMAU(hA1[3], hB1[3], rb0, rb1, rb2) SB       \
    FMAU(hA2[0], hB2[0], rc0, rc1, rc2) SB                                    \
    FMAU(hA2[1], hB2[1], ra0, ra1, ra2) SB

// gate pre-activation: prefetch units 0 and 1, init t from W/b (their loads
// hide under the init FMAs), then windowed dot.
#define GATE1_2(g)                                                            \
    LDU(Rq_, g, 0, ra0, ra1, ra2)                                             \
    LDU(Rq_, g, 1, rb0, rb1, rb2)                                             \
    {   const floatx4 w0_ = Wq_[(g)*3+0], w1_ = Wq_[(g)*3+1],                 \
                      w2_ = Wq_[(g)*3+2];                                     \
        const floatx4 b0_ = Bq_[(g)*3+0], b1_ = Bq_[(g)*3+1],                 \
                      b2_ = Bq_[(g)*3+2];                                     \
        tA0 = EFMA(xsA_, w0_, b0_); tB0 = EFMA(xsB_, w0_, b0_);               \
        tA1 = EFMA(xsA_, w1_, b1_); tB1 = EFMA(xsB_, w1_, b1_);               \
        tA2 = EFMA(xsA_, w2_, b2_); tB2 = EFMA(xsB_, w2_, b2_); } SB          \
    REC10_2T(Rq_, g)

#define STEP1_2(xa, xb)                                                       \
    {   int lof_ = 0;                                                         \
        asm volatile("" : "+v"(lof_));    /* block LICM of invariant loads */ \
        const floatx4* Rq_ = (const floatx4*)(smem + lof_);                   \
        const floatx4* Wq_ = (const floatx4*)(smem + 480 + lof_);             \
        const floatx4* Bq_ = (const floatx4*)(smem + 528 + lof_);             \
        const float xa_ = (xa), xb_ = (xb);                                   \
        const floatx4 xsA_ = {xa_, xa_, xa_, xa_};                            \
        const floatx4 xsB_ = {xb_, xb_, xb_, xb_};                            \
        floatx4 tA0, tA1, tA2, tB0, tB1, tB2;                                 \
        floatx4 pA0, pA1, pA2, pB0, pB1, pB2;                                 \
        floatx4 qA0, qA1, qA2, qB0, qB1, qB2;                                 \
        floatx4 ra0, ra1, ra2, rb0, rb1, rb2, rc0, rc1, rc2;                  \
        GATE1_2(2)   /* g: relu */                                            \
        pA0 = EMAX(tA0, zero4); pA1 = EMAX(tA1, zero4); pA2 = EMAX(tA2, zero4);\
        pB0 = EMAX(tB0, zero4); pB1 = EMAX(tB1, zero4); pB2 = EMAX(tB2, zero4);\
        SB                                                                    \
        GATE1_2(0)   /* i */                                                  \
        SIG3(qA0, qA1, qA2, tA0, tA1, tA2)                                    \
        SIG3(qB0, qB1, qB2, tB0, tB1, tB2)                                    \
        pA0 *= qA0; pA1 *= qA1; pA2 *= qA2;                                   \
        pB0 *= qB0; pB1 *= qB1; pB2 *= qB2; SB                                \
        GATE1_2(1)   /* f */                                                  \
        SIG3(qA0, qA1, qA2, tA0, tA1, tA2)                                    \
        SIG3(qB0, qB1, qB2, tB0, tB1, tB2)                                    \
        cA0 = EFMA(qA0, cA0, pA0); cA1 = EFMA(qA1, cA1, pA1);                 \
        cA2 = EFMA(qA2, cA2, pA2);                                            \
        cB0 = EFMA(qB0, cB0, pB0); cB1 = EFMA(qB1, cB1, pB1);                 \
        cB2 = EFMA(qB2, cB2, pB2); SB                                         \
        GATE1_2(3)   /* o (dot uses old h; h written after) */                \
        SIG3(qA0, qA1, qA2, tA0, tA1, tA2)                                    \
        SIG3(qB0, qB1, qB2, tB0, tB1, tB2)                                    \
        hA0 = qA0 * EMAX(cA0, zero4); hA1 = qA1 * EMAX(cA1, zero4);           \
        hA2 = qA2 * EMAX(cA2, zero4);                                         \
        hB0 = qB0 * EMAX(cB0, zero4); hB1 = qB1 * EMAX(cB1, zero4);           \
        hB2 = qB2 * EMAX(cB2, zero4); SB                                      \
    }

// min=2 keeps the RA budget that produced the clean M=2 schedule (round 14);
// no max so residency follows actual VGPR use.
__global__ __launch_bounds__(BLK) __attribute__((amdgpu_waves_per_eu(2)))
void lstm_ae_kernel(const float* __restrict__ X, const float* __restrict__ ws,
                    const float* __restrict__ bd, float* __restrict__ out, int B)
{
    __shared__ __align__(16) float smem[WS_FLOATS];    // 6.4 KB
    for (int i = threadIdx.x; i < WS_FLOATS; i += BLK) smem[i] = ws[i];
    __syncthreads();

    // M=2: rows b0 (element A) and b1 = b0 + BLK (element B)
    const int base = blockIdx.x * (2 * BLK);
    const int b0 = base + threadIdx.x;
    if (b0 >= B) return;
    int b1 = b0 + BLK;
    if (b1 >= B) b1 = b0;     // benign duplicate in non-exact tails

    const floatx4 zero4 = {0.0f, 0.0f, 0.0f, 0.0f};

    // ---------------- LSTM 1: 50 steps, 2 elements/thread ----------------
    floatx4 hA0 = zero4, hA1 = zero4, hA2 = zero4;
    floatx4 cA0 = zero4, cA1 = zero4, cA2 = zero4;
    floatx4 hB0 = zero4, hB1 = zero4, hB2 = zero4;
    floatx4 cB0 = zero4, cB1 = zero4, cB2 = zero4;

    const float2* __restrict__ xpa = (const float2*)(X + (size_t)b0 * TIN);
    const float2* __restrict__ xpb = (const float2*)(X + (size_t)b1 * TIN);
    float2 va = xpa[0], vb = xpb[0];
    #pragma unroll 1
    for (int p = 0; p < TIN / 2 - 1; ++p) {
        const float2 na = xpa[p + 1], nb = xpb[p + 1];
        STEP1_2(va.x, vb.x)
        STEP1_2(va.y, vb.y)
        va = na; vb = nb;
    }
    STEP1_2(va.x, vb.x)
    STEP1_2(va.y, vb.y)

    // ---------------- tails, sequential per element ----------------
    const float bd0 = bd[0];
    tail_one(smem, hA0, hA1, hA2, bd0, out + (size_t)b0 * 3);
    tail_one(smem, hB0, hB1, hB2, bd0, out + (size_t)b1 * 3);
}

extern "C" void kernel_launch(void* const* d_in, const int* in_sizes, int n_in,
                              void* d_out, int out_size, void* d_ws, size_t ws_size,
                              hipStream_t stream) {
    const float* X  = (const float*)d_in[0];
    const float* W1 = (const float*)d_in[1];
    const float* R1 = (const float*)d_in[2];
    const float* b1 = (const float*)d_in[3];
    const float* W2 = (const float*)d_in[4];
    const float* R2 = (const float*)d_in[5];
    const float* b2 = (const float*)d_in[6];
    const float* Wd = (const float*)d_in[7];
    const float* bd = (const float*)d_in[8];
    float* out = (float*)d_out;
    float* ws  = (float*)d_ws;

    const int B = in_sizes[0] / TIN;   // 524288
    prep_weights<<<1, BLK, 0, stream>>>(W1, R1, b1, W2, R2, b2, Wd, ws);
    const int grid = (B + 2 * BLK - 1) / (2 * BLK);   // 1024
    lstm_ae_kernel<<<grid, BLK, 0, stream>>>(X, ws, bd, out, B);
}

// Round 18
// 397.592 us; speedup vs baseline: 1.1113x; 1.1113x over previous
//
#include <hip/hip_runtime.h>

constexpr int TIN = 50;
constexpr int BLK = 256;
constexpr float NEG_LOG2E = -1.44269504088896341f;

typedef float floatx4 __attribute__((ext_vector_type(4)));
typedef float floatx2 __attribute__((ext_vector_type(2)));

// ws float layout (16B-aligned, gate-major, 10->12 pad so rows stay aligned).
// k = gate*12 + j, gate {0:i,1:f,2:g,3:o}; i/f/o cols pre-scaled by -log2(e)
// so sigmoid(z) = rcp(1 + exp2(z')). Compute reads only the 10 real lanes
// (2 x b128 + 1 x b64 per row; +8-float offset is still 16B-aligned).
//   0    R1p[10][48]
//   480  W1p[48]
//   528  b1p[48]
//   576  W2p[10][48]
//   1056 b2p[48]
//   1104 R2p[10][48]
//   1584 Wdp[12]
constexpr int WS_FLOATS = 1596;

__global__ void prep_weights(const float* __restrict__ W1, const float* __restrict__ R1,
                             const float* __restrict__ b1, const float* __restrict__ W2,
                             const float* __restrict__ R2, const float* __restrict__ b2,
                             const float* __restrict__ Wd, float* __restrict__ ws)
{
    const int tid = threadIdx.x;
    for (int i = tid; i < 480; i += BLK) {
        const int u = i / 48, k = i % 48, gate = k / 12, j = k % 12;
        const float sg = (gate == 2) ? 1.0f : NEG_LOG2E;
        ws[i]        = (j < 10) ? R1[u * 40 + gate * 10 + j] * sg : 0.0f;
        ws[576 + i]  = (j < 10) ? W2[u * 40 + gate * 10 + j] * sg : 0.0f;
        ws[1104 + i] = (j < 10) ? R2[u * 40 + gate * 10 + j] * sg : 0.0f;
    }
    for (int k = tid; k < 48; k += BLK) {
        const int gate = k / 12, j = k % 12;
        const float sg = (gate == 2) ? 1.0f : NEG_LOG2E;
        ws[480 + k]  = (j < 10) ? W1[gate * 10 + j] * sg : 0.0f;
        ws[528 + k]  = (j < 10) ? b1[gate * 10 + j] * sg : 0.0f;
        ws[1056 + k] = (j < 10) ? b2[gate * 10 + j] * sg : 0.0f;
    }
    if (tid < 12) ws[1584 + tid] = (tid < 10) ? Wd[tid] : 0.0f;
}

#define EFMA __builtin_elementwise_fma
#define EMAX __builtin_elementwise_max
#define SB   __builtin_amdgcn_sched_barrier(0);

#define SIGQ(dst, src)                                                        \
    dst[0] = __builtin_amdgcn_rcpf(1.0f + __builtin_amdgcn_exp2f((src)[0]));  \
    dst[1] = __builtin_amdgcn_rcpf(1.0f + __builtin_amdgcn_exp2f((src)[1]));  \
    dst[2] = __builtin_amdgcn_rcpf(1.0f + __builtin_amdgcn_exp2f((src)[2]));  \
    dst[3] = __builtin_amdgcn_rcpf(1.0f + __builtin_amdgcn_exp2f((src)[3]));

#define SIGP(dst, src)                                                        \
    dst[0] = __builtin_amdgcn_rcpf(1.0f + __builtin_amdgcn_exp2f((src)[0]));  \
    dst[1] = __builtin_amdgcn_rcpf(1.0f + __builtin_amdgcn_exp2f((src)[1]));

#define SIG3(d0, d1, d2, s0, s1, s2) SIGQ(d0, s0) SIGQ(d1, s1) SIGQ(d2, s2)

// ---------------- single-element building blocks (tail; = round 14/16) ------
#define RECQ(RB, g, u, HV, t0, t1, t2)                                        \
    {   const float h_ = (HV);                                                \
        const floatx4 hs_ = {h_, h_, h_, h_};                                 \
        t0 = EFMA(hs_, RB[(u) * 12 + (g) * 3 + 0], t0);                       \
        t1 = EFMA(hs_, RB[(u) * 12 + (g) * 3 + 1], t1);                       \
        t2 = EFMA(hs_, RB[(u) * 12 + (g) * 3 + 2], t2); }

#define REC10(RB, g, H0, H1, H2, t0, t1, t2)                                  \
    RECQ(RB, g, 0, (H0)[0], t0, t1, t2) RECQ(RB, g, 1, (H0)[1], t0, t1, t2) SB\
    RECQ(RB, g, 2, (H0)[2], t0, t1, t2) RECQ(RB, g, 3, (H0)[3], t0, t1, t2) SB\
    RECQ(RB, g, 4, (H1)[0], t0, t1, t2) RECQ(RB, g, 5, (H1)[1], t0, t1, t2) SB\
    RECQ(RB, g, 6, (H1)[2], t0, t1, t2) RECQ(RB, g, 7, (H1)[3], t0, t1, t2) SB\
    RECQ(RB, g, 8, (H2)[0], t0, t1, t2) RECQ(RB, g, 9, (H2)[1], t0, t1, t2) SB

#define XZG(g, x0, x1, x2)                                                    \
    x0 = B2q_[(g) * 3 + 0]; x1 = B2q_[(g) * 3 + 1]; x2 = B2q_[(g) * 3 + 2];   \
    REC10(W2q_, g, hq0, hq1, hq2, x0, x1, x2)

#define GATE2(g, i0, i1, i2, t0, t1, t2)                                      \
    t0 = i0; t1 = i1; t2 = i2;                                                \
    REC10(R2q_, g, ho0, ho1, ho2, t0, t1, t2)

#define STEP2T                                                                \
    {   const floatx4 ho0 = h2q0, ho1 = h2q1, ho2 = h2q2;                     \
        floatx4 tt0, tt1, tt2, pp0, pp1, pp2, qq0, qq1, qq2;                  \
        GATE2(2, xqg0, xqg1, xqg2, tt0, tt1, tt2)                             \
        pp0 = EMAX(tt0, zero4); pp1 = EMAX(tt1, zero4);                       \
        pp2 = EMAX(tt2, zero4); SB                                            \
        GATE2(0, xqi0, xqi1, xqi2, tt0, tt1, tt2)                             \
        SIG3(qq0, qq1, qq2, tt0, tt1, tt2)                                    \
        pp0 *= qq0; pp1 *= qq1; pp2 *= qq2; SB                                \
        GATE2(1, xqf0, xqf1, xqf2, tt0, tt1, tt2)                             \
        SIG3(qq0, qq1, qq2, tt0, tt1, tt2)                                    \
        c2q0 = EFMA(qq0, c2q0, pp0); c2q1 = EFMA(qq1, c2q1, pp1);             \
        c2q2 = EFMA(qq2, c2q2, pp2); SB                                       \
        GATE2(3, xqo0, xqo1, xqo2, tt0, tt1, tt2)                             \
        SIG3(qq0, qq1, qq2, tt0, tt1, tt2)                                    \
        h2q0 = qq0 * EMAX(c2q0, zero4); h2q1 = qq1 * EMAX(c2q1, zero4);       \
        h2q2 = qq2 * EMAX(c2q2, zero4); SB                                    \
    }

#define DOUT(dst)                                                             \
    {   floatx4 dv_ = h2q0 * Wdq_[0];                                         \
        dv_ = EFMA(h2q1, Wdq_[1], dv_);                                       \
        dv_ = EFMA(h2q2, Wdq_[2], dv_);                                       \
        dst = dv_[0] + dv_[1] + dv_[2] + dv_[3] + bd0; }

// RepeatVector(3) + LSTM2 + Dense for ONE element (all names compile-time).
// Note: REC10 touches only elements [0],[1] of its H2 argument, so passing
// {pair, 0, 0} as hq2 is exact.
__device__ __forceinline__ void tail_one(const float* __restrict__ smem,
                                         floatx4 hq0, floatx4 hq1, floatx4 hq2,
                                         float bd0, float* __restrict__ o3)
{
    const floatx4 zero4 = {0.0f, 0.0f, 0.0f, 0.0f};
    const floatx4* W2q_ = (const floatx4*)(smem + 576);
    const floatx4* B2q_ = (const floatx4*)(smem + 1056);
    const floatx4* R2q_ = (const floatx4*)(smem + 1104);
    const floatx4* Wdq_ = (const floatx4*)(smem + 1584);

    floatx4 xqi0, xqi1, xqi2, xqf0, xqf1, xqf2;
    floatx4 xqg0, xqg1, xqg2, xqo0, xqo1, xqo2;
    XZG(0, xqi0, xqi1, xqi2) SB
    XZG(1, xqf0, xqf1, xqf2) SB
    XZG(2, xqg0, xqg1, xqg2) SB
    XZG(3, xqo0, xqo1, xqo2) SB

    floatx4 c2q0, c2q1, c2q2, h2q0, h2q1, h2q2, q0, q1, q2, s0, s1, s2;
    SIG3(q0, q1, q2, xqi0, xqi1, xqi2)
    c2q0 = q0 * EMAX(xqg0, zero4);
    c2q1 = q1 * EMAX(xqg1, zero4);
    c2q2 = q2 * EMAX(xqg2, zero4);
    SIG3(s0, s1, s2, xqo0, xqo1, xqo2)
    h2q0 = s0 * EMAX(c2q0, zero4);
    h2q1 = s1 * EMAX(c2q1, zero4);
    h2q2 = s2 * EMAX(c2q2, zero4);
    float o0; DOUT(o0)
    float o1; STEP2T DOUT(o1)
    float o2; STEP2T DOUT(o2)
    o3[0] = o0; o3[1] = o1; o3[2] = o2;
}

// ---------------- M=2 main-loop blocks: exact 10-wide, 1-unit lookahead -----
// LDU: one (gate,unit) row = 2 x b128 + 1 x b64 (all 16B-aligned offsets).
#define LDU(RF, g, u, d0, d1, d2p)                                            \
    d0  = *(const floatx4*)((RF) + (u) * 48 + (g) * 12);                      \
    d1  = *(const floatx4*)((RF) + (u) * 48 + (g) * 12 + 4);                  \
    d2p = *(const floatx2*)((RF) + (u) * 48 + (g) * 12 + 8);

// FMAU: consume one row set for both elements (10 lanes = 20 v_fma total).
#define FMAU(HA, HB, r0, r1, r2p)                                             \
    {   const float ha_ = (HA), hb_ = (HB);                                   \
        const floatx4 hav_ = {ha_, ha_, ha_, ha_};                            \
        const floatx4 hbv_ = {hb_, hb_, hb_, hb_};                            \
        const floatx2 hap_ = {ha_, ha_}, hbp_ = {hb_, hb_};                   \
        tA0  = EFMA(hav_, r0,  tA0);  tB0  = EFMA(hbv_, r0,  tB0);            \
        tA1  = EFMA(hav_, r1,  tA1);  tB1  = EFMA(hbv_, r1,  tB1);            \
        tA2p = EFMA(hap_, r2p, tA2p); tB2p = EFMA(hbp_, r2p, tB2p); }

// Windows: {load u+1 ; FMA u ; SB} — ping-pong ra/rb sets (10 regs each).
#define REC10_2T(RF, g)                                                       \
    LDU(RF, g, 1, rb0, rb1, rb2p) FMAU(hA0[0],  hB0[0],  ra0, ra1, ra2p) SB   \
    LDU(RF, g, 2, ra0, ra1, ra2p) FMAU(hA0[1],  hB0[1],  rb0, rb1, rb2p) SB   \
    LDU(RF, g, 3, rb0, rb1, rb2p) FMAU(hA0[2],  hB0[2],  ra0, ra1, ra2p) SB   \
    LDU(RF, g, 4, ra0, ra1, ra2p) FMAU(hA0[3],  hB0[3],  rb0, rb1, rb2p) SB   \
    LDU(RF, g, 5, rb0, rb1, rb2p) FMAU(hA1[0],  hB1[0],  ra0, ra1, ra2p) SB   \
    LDU(RF, g, 6, ra0, ra1, ra2p) FMAU(hA1[1],  hB1[1],  rb0, rb1, rb2p) SB   \
    LDU(RF, g, 7, rb0, rb1, rb2p) FMAU(hA1[2],  hB1[2],  ra0, ra1, ra2p) SB   \
    LDU(RF, g, 8, ra0, ra1, ra2p) FMAU(hA1[3],  hB1[3],  rb0, rb1, rb2p) SB   \
    LDU(RF, g, 9, rb0, rb1, rb2p) FMAU(hA2p[0], hB2p[0], ra0, ra1, ra2p) SB   \
    FMAU(hA2p[1], hB2p[1], rb0, rb1, rb2p) SB

// gate pre-activation: prefetch unit 0; init t from W/b (10 lanes); windowed dot
#define GATE1_2(g)                                                            \
    LDU(Rf_, g, 0, ra0, ra1, ra2p)                                            \
    {   const floatx4 w0_  = *(const floatx4*)(Wf_ + (g) * 12);               \
        const floatx4 w1_  = *(const floatx4*)(Wf_ + (g) * 12 + 4);           \
        const floatx2 w2p_ = *(const floatx2*)(Wf_ + (g) * 12 + 8);           \
        const floatx4 b0_  = *(const floatx4*)(Bf_ + (g) * 12);               \
        const floatx4 b1_  = *(const floatx4*)(Bf_ + (g) * 12 + 4);           \
        const floatx2 b2p_ = *(const floatx2*)(Bf_ + (g) * 12 + 8);           \
        tA0  = EFMA(xsA_,  w0_,  b0_);  tB0  = EFMA(xsB_,  w0_,  b0_);        \
        tA1  = EFMA(xsA_,  w1_,  b1_);  tB1  = EFMA(xsB_,  w1_,  b1_);        \
        tA2p = EFMA(xsA2_, w2p_, b2p_); tB2p = EFMA(xsB2_, w2p_, b2p_); } SB  \
    REC10_2T(Rf_, g)

#define STEP1_2(xa, xb)                                                       \
    {   int lof_ = 0;                                                         \
        asm volatile("" : "+v"(lof_));    /* block LICM of invariant loads */ \
        const float* Rf_ = smem + lof_;                                       \
        const float* Wf_ = smem + 480 + lof_;                                 \
        const float* Bf_ = smem + 528 + lof_;                                 \
        const float xa_ = (xa), xb_ = (xb);                                   \
        const floatx4 xsA_ = {xa_, xa_, xa_, xa_};                            \
        const floatx4 xsB_ = {xb_, xb_, xb_, xb_};                            \
        const floatx2 xsA2_ = {xa_, xa_}, xsB2_ = {xb_, xb_};                 \
        floatx4 tA0, tA1, tB0, tB1;      floatx2 tA2p, tB2p;                  \
        floatx4 pA0, pA1, pB0, pB1;      floatx2 pA2p, pB2p;                  \
        floatx4 qA0, qA1, qB0, qB1;      floatx2 qA2p, qB2p;                  \
        floatx4 ra0, ra1, rb0, rb1;      floatx2 ra2p, rb2p;                  \
        GATE1_2(2)   /* g: relu */                                            \
        pA0 = EMAX(tA0, zero4); pA1 = EMAX(tA1, zero4);                       \
        pA2p = EMAX(tA2p, zero2);                                             \
        pB0 = EMAX(tB0, zero4); pB1 = EMAX(tB1, zero4);                       \
        pB2p = EMAX(tB2p, zero2); SB                                          \
        GATE1_2(0)   /* i */                                                  \
        SIGQ(qA0, tA0) SIGQ(qA1, tA1) SIGP(qA2p, tA2p)                        \
        SIGQ(qB0, tB0) SIGQ(qB1, tB1) SIGP(qB2p, tB2p)                        \
        pA0 *= qA0; pA1 *= qA1; pA2p *= qA2p;                                 \
        pB0 *= qB0; pB1 *= qB1; pB2p *= qB2p; SB                              \
        GATE1_2(1)   /* f */                                                  \
        SIGQ(qA0, tA0) SIGQ(qA1, tA1) SIGP(qA2p, tA2p)                        \
        SIGQ(qB0, tB0) SIGQ(qB1, tB1) SIGP(qB2p, tB2p)                        \
        cA0 = EFMA(qA0, cA0, pA0); cA1 = EFMA(qA1, cA1, pA1);                 \
        cA2p = EFMA(qA2p, cA2p, pA2p);                                        \
        cB0 = EFMA(qB0, cB0, pB0); cB1 = EFMA(qB1, cB1, pB1);                 \
        cB2p = EFMA(qB2p, cB2p, pB2p); SB                                     \
        GATE1_2(3)   /* o (dot uses old h; h written after) */                \
        SIGQ(qA0, tA0) SIGQ(qA1, tA1) SIGP(qA2p, tA2p)                        \
        SIGQ(qB0, tB0) SIGQ(qB1, tB1) SIGP(qB2p, tB2p)                        \
        hA0 = qA0 * EMAX(cA0, zero4); hA1 = qA1 * EMAX(cA1, zero4);           \
        hA2p = qA2p * EMAX(cA2p, zero2);                                      \
        hB0 = qB0 * EMAX(cB0, zero4); hB1 = qB1 * EMAX(cB1, zero4);           \
        hB2p = qB2p * EMAX(cB2p, zero2); SB                                   \
    }

// min=2 keeps the RA budget that produced the clean M=2 schedule (round 14);
// no max so residency follows actual VGPR use.
__global__ __launch_bounds__(BLK) __attribute__((amdgpu_waves_per_eu(2)))
void lstm_ae_kernel(const float* __restrict__ X, const float* __restrict__ ws,
                    const float* __restrict__ bd, float* __restrict__ out, int B)
{
    __shared__ __align__(16) float smem[WS_FLOATS];    // 6.4 KB
    for (int i = threadIdx.x; i < WS_FLOATS; i += BLK) smem[i] = ws[i];
    __syncthreads();

    // M=2: rows b0 (element A) and b1 = b0 + BLK (element B)
    const int base = blockIdx.x * (2 * BLK);
    const int b0 = base + threadIdx.x;
    if (b0 >= B) return;
    int b1 = b0 + BLK;
    if (b1 >= B) b1 = b0;     // benign duplicate in non-exact tails

    const floatx4 zero4 = {0.0f, 0.0f, 0.0f, 0.0f};
    const floatx2 zero2 = {0.0f, 0.0f};

    // ---------------- LSTM 1: 50 steps, 2 elements/thread, 10-wide state ---
    floatx4 hA0 = zero4, hA1 = zero4, cA0 = zero4, cA1 = zero4;
    floatx2 hA2p = zero2, cA2p = zero2;
    floatx4 hB0 = zero4, hB1 = zero4, cB0 = zero4, cB1 = zero4;
    floatx2 hB2p = zero2, cB2p = zero2;

    const float2* __restrict__ xpa = (const float2*)(X + (size_t)b0 * TIN);
    const float2* __restrict__ xpb = (const float2*)(X + (size_t)b1 * TIN);
    float2 va = xpa[0], vb = xpb[0];
    #pragma unroll 1
    for (int p = 0; p < TIN / 2 - 1; ++p) {
        const float2 na = xpa[p + 1], nb = xpb[p + 1];
        STEP1_2(va.x, vb.x)
        STEP1_2(va.y, vb.y)
        va = na; vb = nb;
    }
    STEP1_2(va.x, vb.x)
    STEP1_2(va.y, vb.y)

    // ---------------- tails, sequential per element ----------------
    const float bd0 = bd[0];
    const floatx4 hq2A = {hA2p[0], hA2p[1], 0.0f, 0.0f};
    const floatx4 hq2B = {hB2p[0], hB2p[1], 0.0f, 0.0f};
    tail_one(smem, hA0, hA1, hq2A, bd0, out + (size_t)b0 * 3);
    tail_one(smem, hB0, hB1, hq2B, bd0, out + (size_t)b1 * 3);
}

extern "C" void kernel_launch(void* const* d_in, const int* in_sizes, int n_in,
                              void* d_out, int out_size, void* d_ws, size_t ws_size,
                              hipStream_t stream) {
    const float* X  = (const float*)d_in[0];
    const float* W1 = (const float*)d_in[1];
    const float* R1 = (const float*)d_in[2];
    const float* b1 = (const float*)d_in[3];
    const float* W2 = (const float*)d_in[4];
    const float* R2 = (const float*)d_in[5];
    const float* b2 = (const float*)d_in[6];
    const float* Wd = (const float*)d_in[7];
    const float* bd = (const float*)d_in[8];
    float* out = (float*)d_out;
    float* ws  = (float*)d_ws;

    const int B = in_sizes[0] / TIN;   // 524288
    prep_weights<<<1, BLK, 0, stream>>>(W1, R1, b1, W2, R2, b2, Wd, ws);
    const int grid = (B + 2 * BLK - 1) / (2 * BLK);   // 1024
    lstm_ae_kernel<<<grid, BLK, 0, stream>>>(X, ws, bd, out, B);
}